// Round 1
// baseline (24269.897 us; speedup 1.0000x reference)
//
#include <hip/hip_runtime.h>

// LSTM B=32, T=2048, D=256, H=256. relu(x) -> single-layer LSTM (i,f,g,o).
// Persistent kernel: 16 blocks = 2 batch-groups (16 batches) x 8 parts.
// Part p holds W_ih/W_hh rows for hidden units [32p,32p+32) x 4 gates (128 rows)
// as bf16 MFMA B-fragments in registers.
// R3 change: SELF-VALIDATING TAGGED h PUBLICATION. Each h-pair is a u64
// {tag32 = s+1 | bf16 h1 | bf16 h0} stored with ONE relaxed agent-scope atomic
// (fire-and-forget). Consumers spin directly on the 32 u64 words they consume
// until every tag == s. Removes per-step: s_waitcnt(0) store-ack RT, flag
// publish RT + flag spin, and the trailing __syncthreads. One barrier/step.
// Buffer-reuse safety: a block publishes h(s) only after ALL its waves passed
// the gates barrier (which requires their spin-reads of h(s-1) to be done),
// so parity buffers are never overwritten before all consumers read them.

#define T_STEPS 2048
#define DDIM 256
#define HDIM 256
#define GROUPS 2
#define PARTS 8
#define NBLOCKS (GROUPS * PARTS)
#define NTHREADS 512

typedef __attribute__((ext_vector_type(8))) short short8;
typedef __attribute__((ext_vector_type(4))) float float4_;
typedef __attribute__((ext_vector_type(2))) float float2_;

__device__ inline unsigned short f2bf(float f) {
    unsigned u = __float_as_uint(f);
    return (unsigned short)((u + 0x7fffu + ((u >> 16) & 1u)) >> 16);
}
__device__ inline float sigmoid_f(float x) { return 1.f / (1.f + __expf(-x)); }
// branch-free tanh; correct saturation at +/-inf of exp
__device__ inline float tanh_f(float x) { return 1.f - 2.f / (__expf(2.f * x) + 1.f); }

__global__ __launch_bounds__(NTHREADS, 2)
void lstm_persistent(const float* __restrict__ x,
                     const float* __restrict__ Wih,
                     const float* __restrict__ Whh,
                     const float* __restrict__ bih,
                     const float* __restrict__ bhh,
                     float* __restrict__ out,
                     unsigned long long* __restrict__ hbuf) // [2 grp][2 parity][16 b][128] u64
{
    const int tid  = threadIdx.x;
    const int blk  = blockIdx.x;
    const int g    = blk >> 3;   // batch group
    const int p    = blk & 7;    // part (hidden-unit slice)
    const int w    = tid >> 6;   // wave 0..7, one 16x16 N-tile each
    const int lane = tid & 63;
    const int c16  = lane & 15;
    const int quad = lane >> 4;

    __shared__ float gatesLds[128 * 17];
    __shared__ float biasLds[128];

    if (tid < 128) {
        int n = ((tid >> 5) << 8) + (p << 5) + (tid & 31);
        biasLds[tid] = bih[n] + bhh[n];
    }

    // ---- weight fragment preload (registers, bf16) ----
    const int r_row = (w << 4) + c16;                                // local row 0..127
    const int wrow  = ((r_row >> 5) << 8) + (p << 5) + (r_row & 31); // global W row
    const int k0    = quad << 3;

    short8 wih_f[8], whh_f[8];
#pragma unroll
    for (int kt = 0; kt < 8; ++kt) {
        const float* s1 = Wih + wrow * DDIM + kt * 32 + k0;
        const float* s2 = Whh + wrow * HDIM + kt * 32 + k0;
        short8 v1, v2;
#pragma unroll
        for (int j = 0; j < 8; ++j) { v1[j] = (short)f2bf(s1[j]); v2[j] = (short)f2bf(s2[j]); }
        wih_f[kt] = v1;
        whh_f[kt] = v2;
    }

    // ---- x prefetch: A-frag lane m = lane&15 = batch-in-group ----
    const float* xlane = x + (size_t)(g * 16 + c16) * (size_t)(T_STEPS * DDIM);
    float4_ xraw[16];
#pragma unroll
    for (int kt = 0; kt < 8; ++kt) {
        const float* sx = xlane + kt * 32 + k0;
        xraw[2 * kt]     = *(const float4_*)(sx);
        xraw[2 * kt + 1] = *(const float4_*)(sx + 4);
    }

    // epilogue mapping: threads 0..255, 2 adjacent units each (one u64 h-pair)
    const int b_e = tid & 15;
    const int up  = (tid >> 4) & 15;
    float c0 = 0.f, c1 = 0.f;

    for (int s = 0; s < T_STEPS; ++s) {
        // ---- x convert (relu + bf16) + x-MFMAs: independent of h, off critical path
        short8 xf[8];
#pragma unroll
        for (int kt = 0; kt < 8; ++kt) {
            short8 v;
#pragma unroll
            for (int j = 0; j < 4; ++j) {
                float a = xraw[2 * kt][j];
                float b = xraw[2 * kt + 1][j];
                v[j]     = (short)f2bf(a > 0.f ? a : 0.f);
                v[j + 4] = (short)f2bf(b > 0.f ? b : 0.f);
            }
            xf[kt] = v;
        }
        // 4 accumulator chains (depth 2 per phase) to hide MFMA latency
        float4_ acc[4];
#pragma unroll
        for (int i = 0; i < 4; ++i) acc[i] = (float4_){0.f, 0.f, 0.f, 0.f};
#pragma unroll
        for (int kt = 0; kt < 8; ++kt)
            acc[kt & 3] = __builtin_amdgcn_mfma_f32_16x16x32_bf16(xf[kt], wih_f[kt], acc[kt & 3], 0, 0, 0);

        // prefetch next step's x (overlaps the spin)
        {
            int sn = (s + 1 < T_STEPS) ? s + 1 : s;
            const float* sx = xlane + (size_t)sn * DDIM + k0;
#pragma unroll
            for (int kt = 0; kt < 8; ++kt) {
                xraw[2 * kt]     = *(const float4_*)(sx + kt * 32);
                xraw[2 * kt + 1] = *(const float4_*)(sx + kt * 32 + 4);
            }
        }

        // ---- spin directly on tagged h(s-1) data: tag==s on parity s&1.
        // Each wave independently loads the 32 u64 words its A-fragment needs
        // and retries until all carry the current tag. No flags, no ordering.
        short8 hf[8];
        {
            const unsigned tag = (unsigned)s;
            const unsigned long long* hq =
                hbuf + (size_t)(((g * 2 + (s & 1)) * 16 + c16) * 128 + quad * 4);
            for (;;) {
                unsigned long long q[32];
#pragma unroll
                for (int kt = 0; kt < 8; ++kt)
#pragma unroll
                    for (int i = 0; i < 4; ++i)
                        q[4 * kt + i] = __hip_atomic_load(hq + kt * 16 + i,
                                            __ATOMIC_RELAXED, __HIP_MEMORY_SCOPE_AGENT);
                unsigned chk = 0;
#pragma unroll
                for (int i = 0; i < 32; ++i) chk |= (unsigned)(q[i] >> 32) ^ tag;
                if (!__any(chk != 0)) {
#pragma unroll
                    for (int kt = 0; kt < 8; ++kt) {
                        union { unsigned u[4]; short8 v; } cv;
#pragma unroll
                        for (int i = 0; i < 4; ++i) cv.u[i] = (unsigned)q[4 * kt + i];
                        hf[kt] = cv.v;
                    }
                    break;
                }
            }
        }

#pragma unroll
        for (int kt = 0; kt < 8; ++kt)
            acc[kt & 3] = __builtin_amdgcn_mfma_f32_16x16x32_bf16(hf[kt], whh_f[kt], acc[kt & 3], 0, 0, 0);

        // D layout: col = lane&15 = local row r_row, row = quad*4+j = batch
#pragma unroll
        for (int j = 0; j < 4; ++j)
            gatesLds[r_row * 17 + (quad << 2) + j] =
                (acc[0][j] + acc[1][j]) + (acc[2][j] + acc[3][j]);
        __syncthreads();   // the ONLY barrier per step (gates write -> read)

        // ---- elementwise LSTM cell update: threads 0..255, 2 units each
        if (tid < 256) {
            const int u0 = up << 1, u1 = u0 + 1;
            float gi0 = gatesLds[u0 * 17 + b_e]        + biasLds[u0];
            float gf0 = gatesLds[(32 + u0) * 17 + b_e] + biasLds[32 + u0];
            float gg0 = gatesLds[(64 + u0) * 17 + b_e] + biasLds[64 + u0];
            float go0 = gatesLds[(96 + u0) * 17 + b_e] + biasLds[96 + u0];
            float gi1 = gatesLds[u1 * 17 + b_e]        + biasLds[u1];
            float gf1 = gatesLds[(32 + u1) * 17 + b_e] + biasLds[32 + u1];
            float gg1 = gatesLds[(64 + u1) * 17 + b_e] + biasLds[64 + u1];
            float go1 = gatesLds[(96 + u1) * 17 + b_e] + biasLds[96 + u1];

            c0 = sigmoid_f(gf0) * c0 + sigmoid_f(gi0) * tanh_f(gg0);
            c1 = sigmoid_f(gf1) * c1 + sigmoid_f(gi1) * tanh_f(gg1);
            float h0 = sigmoid_f(go0) * tanh_f(c0);
            float h1 = sigmoid_f(go1) * tanh_f(c1);

            // h publish: single tagged u64, relaxed agent-scope, fire-and-forget.
            // Value depends on the gates reads -> reads retired before store.
            unsigned hv = (unsigned)f2bf(h0) | ((unsigned)f2bf(h1) << 16);
            unsigned long long word = (unsigned long long)hv
                                    | ((unsigned long long)(unsigned)(s + 1) << 32);
            unsigned long long* hd =
                hbuf + (size_t)(((g * 2 + ((s + 1) & 1)) * 16 + b_e) * 128 + p * 16 + up);
            __hip_atomic_store(hd, word, __ATOMIC_RELAXED, __HIP_MEMORY_SCOPE_AGENT);

            float2_ ov = {h0, h1};
            *(float2_*)(out + ((size_t)(g * 16 + b_e) * T_STEPS + (size_t)s) * HDIM + (p << 5) + u0) = ov;
        }
        // no trailing barrier and no waitcnt: next step's spin self-orders.
        // waves 4..7 immediately start step s+1 x-work while 0..3 finish the cell.
    }
}

extern "C" void kernel_launch(void* const* d_in, const int* in_sizes, int n_in,
                              void* d_out, int out_size, void* d_ws, size_t ws_size,
                              hipStream_t stream) {
    (void)in_sizes; (void)n_in; (void)out_size; (void)ws_size;
    const float* x   = (const float*)d_in[0];
    const float* Wih = (const float*)d_in[1];
    const float* Whh = (const float*)d_in[2];
    const float* bih = (const float*)d_in[3];
    const float* bhh = (const float*)d_in[4];
    float* out = (float*)d_out;

    unsigned long long* hbuf = (unsigned long long*)d_ws;  // 2*2*16*128*8 = 65536 B

    hipMemsetAsync(d_ws, 0, 65536, stream);
    hipLaunchKernelGGL(lstm_persistent, dim3(NBLOCKS), dim3(NTHREADS), 0, stream,
                       x, Wih, Whh, bih, bhh, out, hbuf);
}

// Round 4
// 20765.677 us; speedup vs baseline: 1.1688x; 1.1688x over previous
//
#include <hip/hip_runtime.h>

// LSTM B=32, T=2048, D=256, H=256. relu(x) -> single-layer LSTM (i,f,g,o).
// 16 worker blocks = 2 batch-groups x 8 parts; part p holds W_ih/W_hh rows for
// hidden units [32p,32p+32) x 4 gates (128 rows) as bf16 MFMA B-frags in regs.
//
// R6: MEASURED colocation, zero load-bearing assumptions.
//  - NO hwreg reads (R4/R5 suspect #1). Roles from round-robin hint:
//    XCD(blk) = blk%8 -> group g = blocks {b : b&7==g}, 8 parts = b>>3.
//  - Before the loop each group PROBES actual sc0 coherence: 6 rounds of
//    {store token sc0 -> bounded poll for all 8 tokens sc0}. Same-L2 groups
//    pass in ~us; cross-XCD L2s are not coherent so the probe times out
//    (bounded!) -> vote fail. Leader aggregates votes (agent scope, votes
//    always arrive since probes are bounded) -> group-wide verdict.
//       all pass -> FAST: h + counters via sc0 through the shared XCD L2.
//       else     -> SAFE: exact R2 protocol (agent scope via MALL, proven).
//    A hang is structurally impossible: every new wait is bounded or has a
//    guaranteed producer; per-step sc0 spins run only after 6x verified
//    same-L2 coherence.
//  - R3 lesson kept: narrow spins only (1 dword/lane), never wide data-spin.

#define T_STEPS 2048
#define DDIM 256
#define HDIM 256
#define GROUPS 2
#define PARTS 8
#define NTHREADS 512
#define GRID 64

#define PROBE_ROUNDS 6
#define PROBE_BOUND_FIRST 30000
#define PROBE_BOUND_LATER 3000

typedef __attribute__((ext_vector_type(8))) short short8;
typedef __attribute__((ext_vector_type(4))) float float4_;
typedef __attribute__((ext_vector_type(2))) float float2_;
typedef __attribute__((ext_vector_type(4))) unsigned uint4_;

__device__ inline unsigned short f2bf(float f) {
    unsigned u = __float_as_uint(f);
    return (unsigned short)((u + 0x7fffu + ((u >> 16) & 1u)) >> 16);
}
__device__ inline float sigmoid_f(float x) { return 1.f / (1.f + __expf(-x)); }
__device__ inline float tanh_f(float x) { return 1.f - 2.f / (__expf(2.f * x) + 1.f); }

// ---- sc0 (L1-bypass; coherent within one XCD's L2) primitives ----
__device__ __forceinline__ unsigned ld_u32_sc0(const unsigned* p) {
    unsigned v;
    asm volatile("global_load_dword %0, %1, off sc0\n\ts_waitcnt vmcnt(0)"
                 : "=&v"(v) : "v"(p) : "memory");
    return v;
}
__device__ __forceinline__ void st_u32_sc0(unsigned* p, unsigned v) {
    asm volatile("global_store_dword %0, %1, off sc0" :: "v"(p), "v"(v) : "memory");
}
__device__ __forceinline__ void atomic_add_u32(unsigned* p, unsigned v) {
    // non-returning atomic executes at the L2 coherence point
    asm volatile("global_atomic_add %0, %1, off" :: "v"(p), "v"(v) : "memory");
}
// min of 8 u32 at 64B stride (one vmcnt drain) — probe poll
__device__ __forceinline__ unsigned ldmin8_sc0(const unsigned* p) {
    unsigned a0,a1,a2,a3,a4,a5,a6,a7;
    asm volatile(
        "global_load_dword %0, %8, off sc0\n\t"
        "global_load_dword %1, %8, off offset:64 sc0\n\t"
        "global_load_dword %2, %8, off offset:128 sc0\n\t"
        "global_load_dword %3, %8, off offset:192 sc0\n\t"
        "global_load_dword %4, %8, off offset:256 sc0\n\t"
        "global_load_dword %5, %8, off offset:320 sc0\n\t"
        "global_load_dword %6, %8, off offset:384 sc0\n\t"
        "global_load_dword %7, %8, off offset:448 sc0\n\t"
        "s_waitcnt vmcnt(0)"
        : "=&v"(a0), "=&v"(a1), "=&v"(a2), "=&v"(a3),
          "=&v"(a4), "=&v"(a5), "=&v"(a6), "=&v"(a7)
        : "v"(p) : "memory");
    unsigned m = a0 < a1 ? a0 : a1;
    m = a2 < m ? a2 : m;  m = a3 < m ? a3 : m;
    m = a4 < m ? a4 : m;  m = a5 < m ? a5 : m;
    m = a6 < m ? a6 : m;  m = a7 < m ? a7 : m;
    return m;
}
// one 128B h A-frag slice: 8x dwordx4 at 64B stride, single vmcnt drain
__device__ __forceinline__ void ld_hrow_sc0(const char* p, short8 hf[8]) {
    uint4_ a0, a1, a2, a3, a4, a5, a6, a7;
    asm volatile(
        "global_load_dwordx4 %0, %8, off sc0\n\t"
        "global_load_dwordx4 %1, %8, off offset:64 sc0\n\t"
        "global_load_dwordx4 %2, %8, off offset:128 sc0\n\t"
        "global_load_dwordx4 %3, %8, off offset:192 sc0\n\t"
        "global_load_dwordx4 %4, %8, off offset:256 sc0\n\t"
        "global_load_dwordx4 %5, %8, off offset:320 sc0\n\t"
        "global_load_dwordx4 %6, %8, off offset:384 sc0\n\t"
        "global_load_dwordx4 %7, %8, off offset:448 sc0\n\t"
        "s_waitcnt vmcnt(0)"
        : "=&v"(a0), "=&v"(a1), "=&v"(a2), "=&v"(a3),
          "=&v"(a4), "=&v"(a5), "=&v"(a6), "=&v"(a7)
        : "v"(p) : "memory");
    union { uint4_ u; short8 s; } c;
    c.u = a0; hf[0] = c.s;  c.u = a1; hf[1] = c.s;
    c.u = a2; hf[2] = c.s;  c.u = a3; hf[3] = c.s;
    c.u = a4; hf[4] = c.s;  c.u = a5; hf[5] = c.s;
    c.u = a6; hf[6] = c.s;  c.u = a7; hf[7] = c.s;
}

template<bool COLOC>
__device__ __forceinline__ void lstm_loop(
    const float* __restrict__ xlane, float* __restrict__ out,
    char* __restrict__ hbase, unsigned* __restrict__ flags,
    float (*gatesLds)[128 * 17], const float* biasLds,
    short8* wih_f, short8* whh_f, float4_* xraw,
    int g, int p, int tid, int lane, int c16, int quad, int r_row)
{
    const int b_e = tid & 15;
    const int up  = (tid >> 4) & 15;
    const int k0  = quad << 3;
    float c0 = 0.f, c1 = 0.f;

    for (int s = 0; s < T_STEPS; ++s) {
        float* gates = COLOC ? gatesLds[s & 1] : gatesLds[0];

        // ---- x convert (relu+bf16) + x-MFMAs: off the cross-block critical path
        short8 xf[8];
#pragma unroll
        for (int kt = 0; kt < 8; ++kt) {
            short8 v;
#pragma unroll
            for (int j = 0; j < 4; ++j) {
                float a = xraw[2 * kt][j];
                float b = xraw[2 * kt + 1][j];
                v[j]     = (short)f2bf(a > 0.f ? a : 0.f);
                v[j + 4] = (short)f2bf(b > 0.f ? b : 0.f);
            }
            xf[kt] = v;
        }
        float4_ acc[4];
#pragma unroll
        for (int i = 0; i < 4; ++i) acc[i] = (float4_){0.f, 0.f, 0.f, 0.f};
#pragma unroll
        for (int kt = 0; kt < 8; ++kt)
            acc[kt & 3] = __builtin_amdgcn_mfma_f32_16x16x32_bf16(xf[kt], wih_f[kt], acc[kt & 3], 0, 0, 0);

        // prefetch next step's x (latency hidden under the spin)
        {
            int sn = (s + 1 < T_STEPS) ? s + 1 : s;
            const float* sx = xlane + (size_t)sn * DDIM + k0;
#pragma unroll
            for (int kt = 0; kt < 8; ++kt) {
                xraw[2 * kt]     = *(const float4_*)(sx + kt * 32);
                xraw[2 * kt + 1] = *(const float4_*)(sx + kt * 32 + 4);
            }
        }

        // ---- wait until all 8 parts published h(s-1)
        if (COLOC) {
            // per-part counters reach 4*s when part finished step s-1.
            // every wave spins independently (lanes 0..7, one flag each);
            // sc0 = shared-L2 coherent (verified by the probe).
            const unsigned thr = 4u * (unsigned)s;
            if (lane < PARTS) {
                const unsigned* cp = flags + (size_t)(g * PARTS + lane) * 16;
                while (ld_u32_sc0(cp) < thr) { }
            }
        } else {
            if (tid < PARTS) {
                const int* fp = (const int*)(flags + (size_t)(g * PARTS + tid) * 16);
                while (__hip_atomic_load(fp, __ATOMIC_RELAXED, __HIP_MEMORY_SCOPE_AGENT) < s) { }
            }
            __syncthreads();  // compiler barrier: h loads can't hoist above
        }

        // ---- h A-frag loads from parity buffer s&1
        short8 hf[8];
        const char* hb = hbase + (size_t)(((g * 2 + (s & 1)) * 16 + c16) * 512 + quad * 16);
        if (COLOC) {
            ld_hrow_sc0(hb, hf);
        } else {
            const unsigned long long* hq = (const unsigned long long*)hb;
#pragma unroll
            for (int kt = 0; kt < 8; ++kt) {
                unsigned long long q0 = __hip_atomic_load(hq + kt * 8,     __ATOMIC_RELAXED, __HIP_MEMORY_SCOPE_AGENT);
                unsigned long long q1 = __hip_atomic_load(hq + kt * 8 + 1, __ATOMIC_RELAXED, __HIP_MEMORY_SCOPE_AGENT);
                union { unsigned long long q[2]; short8 v; } cvt;
                cvt.q[0] = q0; cvt.q[1] = q1;
                hf[kt] = cvt.v;
            }
        }

#pragma unroll
        for (int kt = 0; kt < 8; ++kt)
            acc[kt & 3] = __builtin_amdgcn_mfma_f32_16x16x32_bf16(hf[kt], whh_f[kt], acc[kt & 3], 0, 0, 0);

        // D layout: col = lane&15 = local row r_row, row = quad*4+j = batch
#pragma unroll
        for (int j = 0; j < 4; ++j)
            gates[r_row * 17 + (quad << 2) + j] =
                (acc[0][j] + acc[1][j]) + (acc[2][j] + acc[3][j]);
        __syncthreads();   // gates write -> cell read

        // ---- elementwise LSTM cell: waves 0..3, 2 adjacent units per thread
        if (tid < 256) {
            const int u0 = up << 1, u1 = u0 + 1;
            float gi0 = gates[u0 * 17 + b_e]        + biasLds[u0];
            float gf0 = gates[(32 + u0) * 17 + b_e] + biasLds[32 + u0];
            float gg0 = gates[(64 + u0) * 17 + b_e] + biasLds[64 + u0];
            float go0 = gates[(96 + u0) * 17 + b_e] + biasLds[96 + u0];
            float gi1 = gates[u1 * 17 + b_e]        + biasLds[u1];
            float gf1 = gates[(32 + u1) * 17 + b_e] + biasLds[32 + u1];
            float gg1 = gates[(64 + u1) * 17 + b_e] + biasLds[64 + u1];
            float go1 = gates[(96 + u1) * 17 + b_e] + biasLds[96 + u1];

            c0 = sigmoid_f(gf0) * c0 + sigmoid_f(gi0) * tanh_f(gg0);
            c1 = sigmoid_f(gf1) * c1 + sigmoid_f(gi1) * tanh_f(gg1);
            float h0 = sigmoid_f(go0) * tanh_f(c0);
            float h1 = sigmoid_f(go1) * tanh_f(c1);

            unsigned hv = (unsigned)f2bf(h0) | ((unsigned)f2bf(h1) << 16);
            unsigned* hd = (unsigned*)(hbase +
                (size_t)(((g * 2 + ((s + 1) & 1)) * 16 + b_e) * 512 + (p * 16 + up) * 4));

            if (COLOC) {
                st_u32_sc0(hd, hv);
                asm volatile("s_waitcnt vmcnt(0)" ::: "memory"); // h stores in L2
                if ((tid & 63) == 0)   // 4 cell waves -> counter += 4 per step
                    atomic_add_u32(flags + (size_t)(g * PARTS + p) * 16, 1u);
                float2_ ov = {h0, h1};  // out store drains later; not on crit path
                *(float2_*)(out + ((size_t)(g * 16 + b_e) * T_STEPS + (size_t)s) * HDIM + (p << 5) + u0) = ov;
            } else {
                __hip_atomic_store(hd, hv, __ATOMIC_RELAXED, __HIP_MEMORY_SCOPE_AGENT);
                float2_ ov = {h0, h1};
                *(float2_*)(out + ((size_t)(g * 16 + b_e) * T_STEPS + (size_t)s) * HDIM + (p << 5) + u0) = ov;
            }
        }

        if (!COLOC) {
            __builtin_amdgcn_s_waitcnt(0);  // h stores ack'd at MALL
            __syncthreads();                // all waves drained before publish
            if (tid == 0)
                __hip_atomic_store((int*)(flags + (size_t)(g * PARTS + p) * 16), s + 1,
                                   __ATOMIC_RELAXED, __HIP_MEMORY_SCOPE_AGENT);
        }
        // COLOC: no trailing barrier; waves 4..7 run ahead into step s+1
        // (gates double-buffered; reuse-safety via the spin threshold).
    }
}

__global__ __launch_bounds__(NTHREADS, 2)
void lstm_persistent(const float* __restrict__ x,
                     const float* __restrict__ Wih,
                     const float* __restrict__ Whh,
                     const float* __restrict__ bih,
                     const float* __restrict__ bhh,
                     float* __restrict__ out,
                     char* __restrict__ hbase,      // [2 grp][2 par][16 b][512B]
                     unsigned* __restrict__ flags,  // [16] @64B: counters/flags
                     unsigned* __restrict__ probe,  // [16] @64B: probe tokens
                     unsigned* __restrict__ votes,  // [16] @64B: 0=unset 1=pass 2=fail
                     unsigned* __restrict__ verdict) // [2] @64B: 0=unset 1=fast 2=safe
{
    const int tid = threadIdx.x;
    const int blk = blockIdx.x;
    if ((blk & 7) >= GROUPS) return;   // helpers exit (uniform per block)
    const int g = blk & 7;             // round-robin hint: blk%8 = XCD
    const int p = blk >> 3;
    const int w    = tid >> 6;
    const int lane = tid & 63;
    const int c16  = lane & 15;
    const int quad = lane >> 4;

    __shared__ float gatesLds[2][128 * 17];
    __shared__ float biasLds[128];
    __shared__ int colocSh;

    if (tid < 128) {
        int n = ((tid >> 5) << 8) + (p << 5) + (tid & 31);
        biasLds[tid] = bih[n] + bhh[n];
    }

    // ---- weight fragment preload (registers, bf16) ----
    const int r_row = (w << 4) + c16;
    const int wrow  = ((r_row >> 5) << 8) + (p << 5) + (r_row & 31);
    const int k0    = quad << 3;

    short8 wih_f[8], whh_f[8];
#pragma unroll
    for (int kt = 0; kt < 8; ++kt) {
        const float* s1 = Wih + wrow * DDIM + kt * 32 + k0;
        const float* s2 = Whh + wrow * HDIM + kt * 32 + k0;
        short8 v1, v2;
#pragma unroll
        for (int j = 0; j < 8; ++j) { v1[j] = (short)f2bf(s1[j]); v2[j] = (short)f2bf(s2[j]); }
        wih_f[kt] = v1;
        whh_f[kt] = v2;
    }

    const float* xlane = x + (size_t)(g * 16 + c16) * (size_t)(T_STEPS * DDIM);
    float4_ xraw[16];
#pragma unroll
    for (int kt = 0; kt < 8; ++kt) {
        const float* sx = xlane + kt * 32 + k0;
        xraw[2 * kt]     = *(const float4_*)(sx);
        xraw[2 * kt + 1] = *(const float4_*)(sx + 4);
    }

    // ---- sc0-coherence probe (bounded) + group verdict ----
    if (tid == 0) {
        unsigned myvote = 1u;  // pass
        unsigned* ptok = probe + (size_t)(g * PARTS + p) * 16;
        const unsigned* pbase = probe + (size_t)(g * PARTS) * 16;
        for (int r = 1; r <= PROBE_ROUNDS && myvote == 1u; ++r) {
            st_u32_sc0(ptok, (unsigned)r);
            asm volatile("s_waitcnt vmcnt(0)" ::: "memory");
            const int bound = (r == 1) ? PROBE_BOUND_FIRST : PROBE_BOUND_LATER;
            int ok = 0;
            for (int it = 0; it < bound; ++it) {
                if (ldmin8_sc0(pbase) >= (unsigned)r) { ok = 1; break; }
            }
            if (!ok) myvote = 2u;  // fail (bounded -> vote always published)
        }
        __hip_atomic_store(votes + (size_t)(g * PARTS + p) * 16, myvote,
                           __ATOMIC_RELAXED, __HIP_MEMORY_SCOPE_AGENT);
        if (p == 0) {
            unsigned agg = 1u;
            for (int i = 0; i < PARTS; ++i) {   // votes ALWAYS arrive (bounded probes)
                unsigned v;
                do {
                    v = __hip_atomic_load(votes + (size_t)(g * PARTS + i) * 16,
                                          __ATOMIC_RELAXED, __HIP_MEMORY_SCOPE_AGENT);
                } while (v == 0u);
                if (v != 1u) agg = 2u;
            }
            __hip_atomic_store(verdict + (size_t)g * 16, agg,
                               __ATOMIC_RELAXED, __HIP_MEMORY_SCOPE_AGENT);
        }
        unsigned fin;                            // leader ALWAYS publishes
        do {
            fin = __hip_atomic_load(verdict + (size_t)g * 16,
                                    __ATOMIC_RELAXED, __HIP_MEMORY_SCOPE_AGENT);
        } while (fin == 0u);
        colocSh = (fin == 1u);
    }
    __syncthreads();

    if (colocSh)
        lstm_loop<true >(xlane, out, hbase, flags, gatesLds, biasLds,
                         wih_f, whh_f, xraw, g, p, tid, lane, c16, quad, r_row);
    else
        lstm_loop<false>(xlane, out, hbase, flags, gatesLds, biasLds,
                         wih_f, whh_f, xraw, g, p, tid, lane, c16, quad, r_row);
}

extern "C" void kernel_launch(void* const* d_in, const int* in_sizes, int n_in,
                              void* d_out, int out_size, void* d_ws, size_t ws_size,
                              hipStream_t stream) {
    (void)in_sizes; (void)n_in; (void)out_size; (void)ws_size;
    const float* x   = (const float*)d_in[0];
    const float* Wih = (const float*)d_in[1];
    const float* Whh = (const float*)d_in[2];
    const float* bih = (const float*)d_in[3];
    const float* bhh = (const float*)d_in[4];
    float* out = (float*)d_out;

    char*     hbase   = (char*)d_ws;                         // 32768 B
    unsigned* flags   = (unsigned*)((char*)d_ws + 32768);    // 16 x 64 B
    unsigned* probe   = (unsigned*)((char*)d_ws + 33792);    // 16 x 64 B
    unsigned* votes   = (unsigned*)((char*)d_ws + 34816);    // 16 x 64 B
    unsigned* verdict = (unsigned*)((char*)d_ws + 35840);    // 2 x 64 B

    hipMemsetAsync(d_ws, 0, 35968, stream);
    hipLaunchKernelGGL(lstm_persistent, dim3(GRID), dim3(NTHREADS), 0, stream,
                       x, Wih, Whh, bih, bhh, out, hbase, flags, probe, votes, verdict);
}

// Round 5
// 18153.897 us; speedup vs baseline: 1.3369x; 1.1439x over previous
//
#include <hip/hip_runtime.h>

// LSTM B=32, T=2048, D=256, H=256. relu(x) -> single-layer LSTM (i,f,g,o).
//
// R7: ELIMINATE per-step inter-block sync (R6 falsified the latency-scope
// theory: local-L2 fast path engaged, FETCH 402->52MB, yet SLOWER. The cost is
// the 16-block synchronized step structure itself).
// New structure:
//   PHASE 1 (1024 blocks): xg = relu(x)@Wih^T + (bih+bhh) for all (b,t),
//     written to workspace PRE-SWIZZLED into phase-2 per-lane accumulator
//     layout. One-time device-scope arrival counter (coarse; provably safe).
//   PHASE 2 (2 blocks, one per 16-batch group, 1 CU each): the full recurrence
//     with ZERO inter-block traffic. Whh bf16 frags: kt{0,1} in registers,
//     kt{2,3} in LDS, kt{4..7} streamed per step from XCD L2 (read-only,
//     stays resident). Cell fully in registers; h broadcast via LDS double
//     buffer; ONE __syncthreads per step.
// Fallback: if ws_size < 256.5MB, launch the proven R2 kernel (18.1ms).

#define T_STEPS 2048
#define DDIM 256
#define HDIM 256
#define NTHREADS 512
#define GROUPS 2
#define PARTS 8
#define P1_GRID 1024
#define DONE_TARGET 1024

typedef __attribute__((ext_vector_type(8))) short short8;
typedef __attribute__((ext_vector_type(4))) float float4_;
typedef __attribute__((ext_vector_type(2))) float float2_;

// workspace layout (primary path)
#define XG_BYTES   ((size_t)2 * T_STEPS * 64 * 64 * 16)      // 268435456
#define WSW_OFF    XG_BYTES
#define WSW_BYTES  ((size_t)2 * 4 * 64 * 64 * 16)            // 524288
#define DONE_OFF   (WSW_OFF + WSW_BYTES)
#define WS_NEED    (DONE_OFF + 64)

__device__ inline unsigned short f2bf(float f) {
    unsigned u = __float_as_uint(f);
    return (unsigned short)((u + 0x7fffu + ((u >> 16) & 1u)) >> 16);
}
__device__ inline float sigmoid_f(float x) { return 1.f / (1.f + __expf(-x)); }
__device__ inline float tanh_f(float x) { return 1.f - 2.f / (__expf(2.f * x) + 1.f); }

// ======================= PRIMARY: two-phase kernel =======================

__global__ __launch_bounds__(NTHREADS, 2)
void lstm_twophase(const float* __restrict__ x,
                   const float* __restrict__ Wih,
                   const float* __restrict__ Whh,
                   const float* __restrict__ bih,
                   const float* __restrict__ bhh,
                   float* __restrict__ out,
                   char* __restrict__ ws)
{
    float*    xg   = (float*)ws;
    char*     wsw  = ws + WSW_OFF;
    unsigned* done = (unsigned*)(ws + DONE_OFF);

    const int tid  = threadIdx.x;
    const int blk  = blockIdx.x;
    const int w    = tid >> 6;    // wave 0..7
    const int lane = tid & 63;
    const int c16  = lane & 15;
    const int quad = lane >> 4;

    // 128 frags x 64 lanes x 16B = 128KB. Phase 1: Wih staging (f = nt*8+kt).
    // Phase 2: Whh kt{2,3} ((kt-2)*64 + n).
    __shared__ short8 fragLds[128][64];
    // h double buffer: [2][16 batches][132 u32] (528B row stride: 16B-aligned,
    // bank shift 4/row -> conflict-light b128 reads)
    __shared__ unsigned hLds[2][16][132];

    // ---------------- PHASE 1: xg = relu(x)@Wih^T + bias ----------------
    {
        const int g     = blk & 1;
        const int rem   = blk >> 1;      // 0..511
        const int chunk = rem >> 2;      // 0..127 (16 timesteps each)
        const int nq    = rem & 3;       // N quarter (16 tiles)
        const int nt0   = nq * 16;

        // stage this quarter's Wih bf16 B-frags into LDS (each frag once)
        for (int f = w * 16; f < w * 16 + 16; ++f) {
            const int nt = f >> 3, kt = f & 7;
            const float* src = Wih + (size_t)((nt0 + nt) * 16 + c16) * DDIM + kt * 32 + quad * 8;
            short8 v;
#pragma unroll
            for (int j = 0; j < 8; ++j) v[j] = (short)f2bf(src[j]);
            fragLds[f][lane] = v;
        }
        __syncthreads();

#pragma unroll 1
        for (int mi = 0; mi < 2; ++mi) {
            const int t = chunk * 16 + (w * 2 + mi);
            // A-frags (relu + bf16), lane c16 = batch
            const float* xrow = x + ((size_t)(g * 16 + c16) * T_STEPS + t) * DDIM + quad * 8;
            short8 af[8];
#pragma unroll
            for (int kt = 0; kt < 8; ++kt) {
                short8 v;
#pragma unroll
                for (int j = 0; j < 8; ++j) {
                    float a = xrow[kt * 32 + j];
                    v[j] = (short)f2bf(a > 0.f ? a : 0.f);
                }
                af[kt] = v;
            }
#pragma unroll 1
            for (int ng = 0; ng < 2; ++ng) {
                float4_ acc[8];
#pragma unroll
                for (int i = 0; i < 8; ++i) acc[i] = (float4_){0.f, 0.f, 0.f, 0.f};
#pragma unroll
                for (int kt = 0; kt < 8; ++kt)
#pragma unroll
                    for (int i = 0; i < 8; ++i)
                        acc[i] = __builtin_amdgcn_mfma_f32_16x16x32_bf16(
                            af[kt], fragLds[(ng * 8 + i) * 8 + kt][lane], acc[i], 0, 0, 0);
#pragma unroll
                for (int i = 0; i < 8; ++i) {
                    const int n  = nt0 + ng * 8 + i;        // global N-tile 0..63
                    const float bias = bih[n * 16 + c16] + bhh[n * 16 + c16];
#pragma unroll
                    for (int j = 0; j < 4; ++j) acc[i][j] += bias;
                    // pre-swizzled: slot (w2 = n&7, a = n>>3) matches phase 2
                    float4_* dst = (float4_*)xg +
                        (((size_t)g * T_STEPS + t) * 64 + (n & 7) * 8 + (n >> 3)) * 64 + lane;
                    *dst = acc[i];
                }
            }
        }
        __syncthreads();            // all waves' stores ack'd at L2
        if (tid == 0) {
            __threadfence();        // L2 writeback -> device-visible
            atomicAdd(done, 1u);
        }
    }

    if (blk >= 2) return;

    // ---------------- PHASE 2 setup (no dependency on other blocks) -------
    const int g = blk;

    // register B-frags kt{0,1}: tile n = w + 8a
    short8 wf[2][8];
#pragma unroll
    for (int kt = 0; kt < 2; ++kt)
#pragma unroll
        for (int a = 0; a < 8; ++a) {
            const int n = w + 8 * a;
            const float* src = Whh + (size_t)(n * 16 + c16) * HDIM + kt * 32 + quad * 8;
            short8 v;
#pragma unroll
            for (int j = 0; j < 8; ++j) v[j] = (short)f2bf(src[j]);
            wf[kt][a] = v;
        }
    // LDS B-frags kt{2,3} (fragLds reuse: safe, past phase-1 barrier)
#pragma unroll
    for (int kt = 2; kt < 4; ++kt)
#pragma unroll
        for (int a = 0; a < 8; ++a) {
            const int n = w + 8 * a;
            const float* src = Whh + (size_t)(n * 16 + c16) * HDIM + kt * 32 + quad * 8;
            short8 v;
#pragma unroll
            for (int j = 0; j < 8; ++j) v[j] = (short)f2bf(src[j]);
            fragLds[(kt - 2) * 64 + n][lane] = v;
        }
    // L2-streamed B-frags kt{4..7}: private swizzled copy in workspace
#pragma unroll
    for (int kt = 4; kt < 8; ++kt)
#pragma unroll
        for (int a = 0; a < 8; ++a) {
            const int n = w + 8 * a;
            const float* src = Whh + (size_t)(n * 16 + c16) * HDIM + kt * 32 + quad * 8;
            short8 v;
#pragma unroll
            for (int j = 0; j < 8; ++j) v[j] = (short)f2bf(src[j]);
            *(short8*)(wsw + ((((size_t)blk * 4 + (kt - 4)) * 64 + n) * 64 + lane) * 16) = v;
        }
    // zero h buffers (h0 = 0)
    for (int i = tid; i < 2 * 16 * 132; i += NTHREADS) ((unsigned*)hLds)[i] = 0u;

    // one-time wait for phase 1 (acquire -> L2 invalidate before xg reads)
    if (tid == 0) {
        while (__hip_atomic_load(done, __ATOMIC_ACQUIRE, __HIP_MEMORY_SCOPE_AGENT)
               < DONE_TARGET) { }
    }
    __syncthreads();

    const float4_* xg4 = (const float4_*)xg;
    float4_ xgbuf[8];
#pragma unroll
    for (int a = 0; a < 8; ++a)
        xgbuf[a] = xg4[(((size_t)g * T_STEPS + 0) * 64 + w * 8 + a) * 64 + lane];

    float c_[8];
#pragma unroll
    for (int i = 0; i < 8; ++i) c_[i] = 0.f;

    float* outg = out + (size_t)(g * 16) * T_STEPS * HDIM;
    const char* wswB = wsw + (size_t)blk * 4 * 64 * 64 * 16;

    // ---------------- PHASE 2 main loop: 1 barrier/step, all in one CU ----
    for (int s = 0; s < T_STEPS; ++s) {
        float4_ acc[8];
#pragma unroll
        for (int a = 0; a < 8; ++a) acc[a] = xgbuf[a];
        // prefetch next step's xg (latency hidden under this step)
        const int sn = (s + 1 < T_STEPS) ? s + 1 : s;
#pragma unroll
        for (int a = 0; a < 8; ++a)
            xgbuf[a] = xg4[(((size_t)g * T_STEPS + sn) * 64 + w * 8 + a) * 64 + lane];

        // h A-frags from LDS parity buffer: lane c16 = batch row
        const char* hbase = (const char*)hLds + (s & 1) * (16 * 132 * 4)
                          + c16 * 528 + quad * 16;

        // kt 0..1: B from registers
#pragma unroll
        for (int kt = 0; kt < 2; ++kt) {
            const short8 ha = *(const short8*)(hbase + kt * 64);
#pragma unroll
            for (int a = 0; a < 8; ++a)
                acc[a] = __builtin_amdgcn_mfma_f32_16x16x32_bf16(ha, wf[kt][a], acc[a], 0, 0, 0);
        }
        // kt 2..3: B from LDS
#pragma unroll
        for (int kt = 2; kt < 4; ++kt) {
            const short8 ha = *(const short8*)(hbase + kt * 64);
#pragma unroll
            for (int a = 0; a < 8; ++a)
                acc[a] = __builtin_amdgcn_mfma_f32_16x16x32_bf16(
                    ha, fragLds[(kt - 2) * 64 + (w + 8 * a)][lane], acc[a], 0, 0, 0);
        }
        // kt 4..7: B streamed from XCD L2 (weights resident after step 0)
#pragma unroll
        for (int kt = 4; kt < 8; ++kt) {
            const short8 ha = *(const short8*)(hbase + kt * 64);
#pragma unroll
            for (int a = 0; a < 8; ++a) {
                const short8 bv = *(const short8*)(wswB +
                    (((size_t)(kt - 4) * 64 + (w + 8 * a)) * 64 + lane) * 16);
                acc[a] = __builtin_amdgcn_mfma_f32_16x16x32_bf16(ha, bv, acc[a], 0, 0, 0);
            }
        }

        // cell: fully in registers. acc[a]: gate = a>>1, idx = a&1,
        // unit u = (w + 8*idx)*16 + c16, batch b = quad*4 + j.
        char* hw = (char*)hLds + ((s + 1) & 1) * (16 * 132 * 4);
#pragma unroll
        for (int idx = 0; idx < 2; ++idx) {
            const int u = (w + 8 * idx) * 16 + c16;
#pragma unroll
            for (int j = 0; j < 4; ++j) {
                const float gi = acc[0 + idx][j];
                const float gf = acc[2 + idx][j];
                const float gg = acc[4 + idx][j];
                const float go = acc[6 + idx][j];
                const float cc = sigmoid_f(gf) * c_[idx * 4 + j]
                               + sigmoid_f(gi) * tanh_f(gg);
                c_[idx * 4 + j] = cc;
                const float h = sigmoid_f(go) * tanh_f(cc);
                const int b = quad * 4 + j;
                outg[((size_t)b * T_STEPS + s) * HDIM + u] = h;
                *(unsigned short*)(hw + b * 528 + u * 2) = f2bf(h);
            }
        }
        __syncthreads();   // h(s+1) visible to all waves; the only barrier
    }
}

// ======================= FALLBACK: proven R2 kernel =======================

__global__ __launch_bounds__(NTHREADS, 2)
void lstm_r2(const float* __restrict__ x, const float* __restrict__ Wih,
             const float* __restrict__ Whh, const float* __restrict__ bih,
             const float* __restrict__ bhh, float* __restrict__ out,
             unsigned int* __restrict__ hbuf, int* __restrict__ flags)
{
    const int tid  = threadIdx.x;
    const int blk  = blockIdx.x;
    const int g    = blk >> 3;
    const int p    = blk & 7;
    const int w    = tid >> 6;
    const int lane = tid & 63;
    const int c16  = lane & 15;
    const int quad = lane >> 4;

    __shared__ float gatesLds[128 * 17];
    __shared__ float biasLds[128];

    if (tid < 128) {
        int n = ((tid >> 5) << 8) + (p << 5) + (tid & 31);
        biasLds[tid] = bih[n] + bhh[n];
    }

    const int r_row = (w << 4) + c16;
    const int wrow  = ((r_row >> 5) << 8) + (p << 5) + (r_row & 31);
    const int k0    = quad << 3;

    short8 wih_f[8], whh_f[8];
#pragma unroll
    for (int kt = 0; kt < 8; ++kt) {
        const float* s1 = Wih + wrow * DDIM + kt * 32 + k0;
        const float* s2 = Whh + wrow * HDIM + kt * 32 + k0;
        short8 v1, v2;
#pragma unroll
        for (int j = 0; j < 8; ++j) { v1[j] = (short)f2bf(s1[j]); v2[j] = (short)f2bf(s2[j]); }
        wih_f[kt] = v1;
        whh_f[kt] = v2;
    }

    const float* xlane = x + (size_t)(g * 16 + c16) * (size_t)(T_STEPS * DDIM);
    float4_ xraw[16];
#pragma unroll
    for (int kt = 0; kt < 8; ++kt) {
        const float* sx = xlane + kt * 32 + k0;
        xraw[2 * kt]     = *(const float4_*)(sx);
        xraw[2 * kt + 1] = *(const float4_*)(sx + 4);
    }

    const int b_e = tid & 15;
    const int up  = (tid >> 4) & 15;
    float c0 = 0.f, c1 = 0.f;
    const int myflag = blk << 4;

    for (int s = 0; s < T_STEPS; ++s) {
        short8 xf[8];
#pragma unroll
        for (int kt = 0; kt < 8; ++kt) {
            short8 v;
#pragma unroll
            for (int j = 0; j < 4; ++j) {
                float a = xraw[2 * kt][j];
                float b = xraw[2 * kt + 1][j];
                v[j]     = (short)f2bf(a > 0.f ? a : 0.f);
                v[j + 4] = (short)f2bf(b > 0.f ? b : 0.f);
            }
            xf[kt] = v;
        }
        float4_ acc0 = {0.f, 0.f, 0.f, 0.f};
        float4_ acc1 = {0.f, 0.f, 0.f, 0.f};
#pragma unroll
        for (int kt = 0; kt < 8; kt += 2) {
            acc0 = __builtin_amdgcn_mfma_f32_16x16x32_bf16(xf[kt],     wih_f[kt],     acc0, 0, 0, 0);
            acc1 = __builtin_amdgcn_mfma_f32_16x16x32_bf16(xf[kt + 1], wih_f[kt + 1], acc1, 0, 0, 0);
        }
        {
            int sn = (s + 1 < T_STEPS) ? s + 1 : s;
            const float* sx = xlane + (size_t)sn * DDIM + k0;
#pragma unroll
            for (int kt = 0; kt < 8; ++kt) {
                xraw[2 * kt]     = *(const float4_*)(sx + kt * 32);
                xraw[2 * kt + 1] = *(const float4_*)(sx + kt * 32 + 4);
            }
        }
        if (tid < PARTS) {
            const int* fp = flags + ((g * PARTS + tid) << 4);
            while (__hip_atomic_load(fp, __ATOMIC_RELAXED, __HIP_MEMORY_SCOPE_AGENT) < s) { }
        }
        __syncthreads();

        const unsigned long long* hq = (const unsigned long long*)
            ((const char*)hbuf + (size_t)(((g * 2 + (s & 1)) * 16 + c16) * 512) + (size_t)(k0 * 2));
        short8 hf[8];
#pragma unroll
        for (int kt = 0; kt < 8; ++kt) {
            unsigned long long q0 = __hip_atomic_load(hq + kt * 8,     __ATOMIC_RELAXED, __HIP_MEMORY_SCOPE_AGENT);
            unsigned long long q1 = __hip_atomic_load(hq + kt * 8 + 1, __ATOMIC_RELAXED, __HIP_MEMORY_SCOPE_AGENT);
            union { unsigned long long q[2]; short8 v; } cvt;
            cvt.q[0] = q0; cvt.q[1] = q1;
            hf[kt] = cvt.v;
        }
#pragma unroll
        for (int kt = 0; kt < 8; kt += 2) {
            acc0 = __builtin_amdgcn_mfma_f32_16x16x32_bf16(hf[kt],     whh_f[kt],     acc0, 0, 0, 0);
            acc1 = __builtin_amdgcn_mfma_f32_16x16x32_bf16(hf[kt + 1], whh_f[kt + 1], acc1, 0, 0, 0);
        }
#pragma unroll
        for (int j = 0; j < 4; ++j)
            gatesLds[r_row * 17 + (quad << 2) + j] = acc0[j] + acc1[j];
        __syncthreads();

        if (tid < 256) {
            const int u0 = up << 1, u1 = (up << 1) + 1;
            float gi0 = gatesLds[u0 * 17 + b_e]         + biasLds[u0];
            float gf0 = gatesLds[(32 + u0) * 17 + b_e]  + biasLds[32 + u0];
            float gg0 = gatesLds[(64 + u0) * 17 + b_e]  + biasLds[64 + u0];
            float go0 = gatesLds[(96 + u0) * 17 + b_e]  + biasLds[96 + u0];
            float gi1 = gatesLds[u1 * 17 + b_e]         + biasLds[u1];
            float gf1 = gatesLds[(32 + u1) * 17 + b_e]  + biasLds[32 + u1];
            float gg1 = gatesLds[(64 + u1) * 17 + b_e]  + biasLds[64 + u1];
            float go1 = gatesLds[(96 + u1) * 17 + b_e]  + biasLds[96 + u1];

            c0 = sigmoid_f(gf0) * c0 + sigmoid_f(gi0) * tanh_f(gg0);
            c1 = sigmoid_f(gf1) * c1 + sigmoid_f(gi1) * tanh_f(gg1);
            float h0 = sigmoid_f(go0) * tanh_f(c0);
            float h1 = sigmoid_f(go1) * tanh_f(c1);

            unsigned hv = (unsigned)f2bf(h0) | ((unsigned)f2bf(h1) << 16);
            unsigned int* hd = hbuf + (((g * 2 + ((s + 1) & 1)) * 16 + b_e) << 7) + (p << 4) + up;
            __hip_atomic_store(hd, hv, __ATOMIC_RELAXED, __HIP_MEMORY_SCOPE_AGENT);

            float2_ ov = {h0, h1};
            *(float2_*)(out + ((size_t)(g * 16 + b_e) * T_STEPS + (size_t)s) * HDIM + (p << 5) + u0) = ov;
        }
        __builtin_amdgcn_s_waitcnt(0);
        __syncthreads();
        if (tid == 0)
            __hip_atomic_store(flags + myflag, s + 1,
                               __ATOMIC_RELAXED, __HIP_MEMORY_SCOPE_AGENT);
    }
}

extern "C" void kernel_launch(void* const* d_in, const int* in_sizes, int n_in,
                              void* d_out, int out_size, void* d_ws, size_t ws_size,
                              hipStream_t stream) {
    (void)in_sizes; (void)n_in; (void)out_size;
    const float* x   = (const float*)d_in[0];
    const float* Wih = (const float*)d_in[1];
    const float* Whh = (const float*)d_in[2];
    const float* bih = (const float*)d_in[3];
    const float* bhh = (const float*)d_in[4];
    float* out = (float*)d_out;

    if (ws_size >= WS_NEED) {
        hipMemsetAsync((char*)d_ws + DONE_OFF, 0, 64, stream);
        hipLaunchKernelGGL(lstm_twophase, dim3(P1_GRID), dim3(NTHREADS), 0, stream,
                           x, Wih, Whh, bih, bhh, out, (char*)d_ws);
    } else {
        unsigned int* hbuf = (unsigned int*)d_ws;
        int* flags         = (int*)((char*)d_ws + 32768);
        hipMemsetAsync(d_ws, 0, 32768 + 16 * 64, stream);
        hipLaunchKernelGGL(lstm_r2, dim3(16), dim3(NTHREADS), 0, stream,
                           x, Wih, Whh, bih, bhh, out, hbuf, flags);
    }
}